// Round 3
// baseline (138.814 us; speedup 1.0000x reference)
//
#include <hip/hip_runtime.h>
#include <cstdint>

// SpatialBorderLoss — R10: persistent grid + per-wave double-buffered DMA
// pipeline with counted vmcnt(9). No barrier in the hot loop.
//
// R9 post-mortem: per-wave wait NEUTRAL (133.28 vs 133.83) -> block barrier
// was already hidden by 4-blocks/CU TLP. New theory: main (~25us vs 17.1us
// floor) is launch-phased — each block drains its loads, computes, exits;
// VMEM idles between block generations. Fix = T3/T4 scaled down: 1024
// persistent blocks (exact residency), each wave pipelines tiles with
// 9 VMEM ops/tile (6 global_load_lds + 2 quad dwordx4 + 1 weight dword)
// and waits vmcnt(9) — next tile's group always in flight during compute.
//
// Counted-wait ledger: prologue issues group(t0)=9. Iter i: issue
// group(t_{i+1})=9, s_waitcnt vmcnt(9) -> drains group(t_i) exactly.
// "memory"-clobber asm pins compiler-scheduled loads on both sides;
// count is order-insensitive within the window. Last iter: vmcnt(0).
// WAR on LDS buffers safe: group(t_{i+2}) issued after compute(t_i)'s
// ds_reads retired (program order + lgkmcnt).
//
// Predict: main 25 -> ~18-19us, total 133.3 -> ~126-128. FETCH unchanged.
// Fail -> vmcnt model wrong, revert R9. Neutral -> roofline (fills dominate).
//
// ws: double part_sum[1024] ; uint part_cnt[1024] ; uint part_wpos[1024]

#define SBL_BLOCK 256
#define SBL_TILE  256
#define SBL_GRID  1024
#define SBL_WAVES (SBL_BLOCK / 64)          // 4
#define SBL_WAVE_BYTES (64 * 72)            // 4608 B per wave per tile
#define SBL_BUF_FLOATS (SBL_TILE * 18)      // 4608 floats = 18432 B per buffer

__device__ __forceinline__ void sbl_issue_dma(const float* pts, int tile_base,
                                              int wave, int lane, uint32_t lds_byte)
{
    const char* g0 = (const char*)pts + (size_t)tile_base * 72 + (size_t)wave * SBL_WAVE_BYTES;
    const uint32_t l0 = lds_byte + (uint32_t)(wave * SBL_WAVE_BYTES);
    #pragma unroll
    for (int i = 0; i < 4; ++i) {                    // 4 x 16B/lane = 4096 B
        __builtin_amdgcn_global_load_lds(
            (const __attribute__((address_space(1))) void*)(g0 + i * 1024 + lane * 16),
            (__attribute__((address_space(3))) void*)(uintptr_t)(l0 + i * 1024 + lane * 16),
            16, 0, 0);
    }
    #pragma unroll
    for (int j = 0; j < 2; ++j) {                    // 2 x 4B/lane = 512 B
        __builtin_amdgcn_global_load_lds(
            (const __attribute__((address_space(1))) void*)(g0 + 4096 + j * 256 + lane * 4),
            (__attribute__((address_space(3))) void*)(uintptr_t)(l0 + 4096 + j * 256 + lane * 4),
            4, 0, 0);
    }
}

__device__ __forceinline__ void sbl_compute_row(const float2* prow, float4 qa, float4 qb,
                                                float& local_sum, unsigned int& pack)
{
    const float vx0 = qa.x, vy0 = qa.y, vx1 = qa.z, vy1 = qa.w;
    const float vx2 = qb.x, vy2 = qb.y, vx3 = qb.z, vy3 = qb.w;
    const float cx = (vx0 + vx2) * 0.5f;
    const float cy = (vy0 + vy2) * 0.5f;
    // edge e pairs (v_e, v_{e-1 mod 4}) per jnp.roll(v,1)
    const float d0 = vy3 - vy0, d1 = vy0 - vy1, d2 = vy1 - vy2, d3 = vy2 - vy3;
    const float e0 = vx3 - vx0, e1 = vx0 - vx1, e2 = vx1 - vx2, e3 = vx2 - vx3;
    const bool  n0 = d0 < 0.0f, n1 = d1 < 0.0f, n2 = d2 < 0.0f, n3 = d3 < 0.0f;

    #pragma unroll
    for (int k = 0; k < 9; ++k) {
        const float2 p = prow[k];
        const float px = p.x, py = p.y;

        const bool c0 = vy0 > py, c1 = vy1 > py, c2 = vy2 > py, c3 = vy3 > py;
        const bool s0 = c0 != c3, s1 = c1 != c0, s2 = c2 != c1, s3 = c3 != c2;

        // straddle pins sign of d; divide -> sign-adjusted mul-compare
        const float t0 = py - vy0, t1 = py - vy1, t2 = py - vy2, t3 = py - vy3;
        const float m0 = e0 * t0, m1 = e1 * t1, m2 = e2 * t2, m3 = e3 * t3;
        const float l0 = (px - vx0) * d0, l1 = (px - vx1) * d1;
        const float l2 = (px - vx2) * d2, l3 = (px - vx3) * d3;

        const bool x0 = s0 && ((l0 < m0) != n0);
        const bool x1 = s1 && ((l1 < m1) != n1);
        const bool x2 = s2 && ((l2 < m2) != n2);
        const bool x3 = s3 && ((l3 < m3) != n3);

        const bool inside = (x0 != x1) != (x2 != x3);   // parity of crossings
        if (!inside) {
            const float dx = px - cx;
            const float dy = py - cy;
            local_sum += sqrtf(fmaf(dx, dx, dy * dy));  // 0.2 applied in finalize
            pack += 1u;
        }
    }
}

__global__ void __launch_bounds__(SBL_BLOCK) sbl_main(
    const float* __restrict__ pts,      // [n,18]
    const float* __restrict__ quads,    // [n,8]
    const float* __restrict__ weight,   // [n]
    double* __restrict__ part_sum,
    unsigned int* __restrict__ part_cnt,
    unsigned int* __restrict__ part_wpos,
    int n)
{
    __shared__ __align__(16) float s_pts[2 * SBL_BUF_FLOATS];   // 36864 B

    const int tid  = threadIdx.x;
    const int lane = tid & 63;
    const int wave = tid >> 6;
    const int bid  = blockIdx.x;
    const int ntiles_full = n / SBL_TILE;            // tiles with all 256 rows

    float local_sum = 0.0f;
    // pack: cnt in [15:0], wpos in [31:16] (per-thread <= ~45 each: fits)
    unsigned int pack = 0u;
    const uint32_t lds0 = (uint32_t)(uintptr_t)(void*)s_pts;

    int t = bid;
    if (t < ntiles_full) {
        // ---- prologue: group(t0) = 6 DMA + 3 reg loads = 9 VMEM ----
        sbl_issue_dma(pts, t * SBL_TILE, wave, lane, lds0);
        {
            const int r = t * SBL_TILE + tid;
            const float4* q4 = reinterpret_cast<const float4*>(quads) + (size_t)r * 2;
            float4 qa_c = q4[0];
            float4 qb_c = q4[1];
            float  wv_c = weight[r];
            int parity = 0;

            while (true) {
                const int  tn = t + SBL_GRID;
                const bool has_next = (tn < ntiles_full);
                float4 qa_n = make_float4(0.f, 0.f, 0.f, 0.f);
                float4 qb_n = make_float4(0.f, 0.f, 0.f, 0.f);
                float  wv_n = 0.0f;
                if (has_next) {
                    sbl_issue_dma(pts, tn * SBL_TILE, wave, lane,
                                  lds0 + (uint32_t)((parity ^ 1) * (SBL_BUF_FLOATS * 4)));
                    const int rn = tn * SBL_TILE + tid;
                    const float4* q4n = reinterpret_cast<const float4*>(quads) + (size_t)rn * 2;
                    qa_n = q4n[0];
                    qb_n = q4n[1];
                    wv_n = weight[rn];
                    asm volatile("s_waitcnt vmcnt(9)" ::: "memory");   // drain group(t) only
                } else {
                    asm volatile("s_waitcnt vmcnt(0)" ::: "memory");   // pipeline tail
                }
                __builtin_amdgcn_sched_barrier(0);

                pack += (wv_c > 0.0f) ? (1u << 16) : 0u;
                const float2* prow = reinterpret_cast<const float2*>(
                    s_pts + parity * SBL_BUF_FLOATS + tid * 18);
                sbl_compute_row(prow, qa_c, qb_c, local_sum, pack);

                if (!has_next) break;
                t = tn; parity ^= 1;
                qa_c = qa_n; qb_c = qb_n; wv_c = wv_n;
            }
        }
    }

    // ---- tail tile (rows < 256): at most one in the grid ----
    const int ttail = ntiles_full;
    if ((size_t)ttail * SBL_TILE < (size_t)n && (ttail % SBL_GRID) == bid) {
        const int base = ttail * SBL_TILE;
        const int rows = n - base;
        __syncthreads();                              // all waves past their reads
        const float2* g2 = reinterpret_cast<const float2*>(pts + (size_t)base * 18);
        float2* s2 = reinterpret_cast<float2*>(s_pts);
        for (int idx = tid; idx < rows * 9; idx += SBL_BLOCK) s2[idx] = g2[idx];
        __syncthreads();
        if (tid < rows) {
            const int r = base + tid;
            const float4* q4 = reinterpret_cast<const float4*>(quads) + (size_t)r * 2;
            const float4 qa = q4[0];
            const float4 qb = q4[1];
            const float  wv = weight[r];
            pack += (wv > 0.0f) ? (1u << 16) : 0u;
            const float2* prow = reinterpret_cast<const float2*>(s_pts + tid * 18);
            sbl_compute_row(prow, qa, qb, local_sum, pack);
        }
    }

    // ---- wave (64) reduction ----
    #pragma unroll
    for (int off = 32; off > 0; off >>= 1) {
        local_sum += __shfl_down(local_sum, off, 64);
        pack      += __shfl_down(pack, off, 64);
    }

    // ---- block reduction across waves ----
    __shared__ float        r_sum[SBL_WAVES];
    __shared__ unsigned int r_pack[SBL_WAVES];
    if (lane == 0) { r_sum[wave] = local_sum; r_pack[wave] = pack; }
    __syncthreads();
    if (tid == 0) {
        double bsum = 0.0;
        unsigned int bcnt = 0u, bwpos = 0u;
        #pragma unroll
        for (int i = 0; i < SBL_WAVES; ++i) {
            bsum  += (double)r_sum[i];
            bcnt  += r_pack[i] & 0xffffu;
            bwpos += r_pack[i] >> 16;
        }
        part_sum[bid]  = bsum;      // own slot: no init, no atomics
        part_cnt[bid]  = bcnt;
        part_wpos[bid] = bwpos;
    }
}

__global__ void __launch_bounds__(1024) sbl_finalize(
    const double* __restrict__ part_sum,
    const unsigned int* __restrict__ part_cnt,
    const unsigned int* __restrict__ part_wpos,
    float* __restrict__ out,
    int nblocks)
{
    const int tid = threadIdx.x;           // 1024 threads = 16 waves
    double s = 0.0;
    unsigned int c = 0u, w = 0u;
    for (int i = tid; i < nblocks; i += 1024) {
        s += part_sum[i];
        c += part_cnt[i];
        w += part_wpos[i];
    }
    #pragma unroll
    for (int off = 32; off > 0; off >>= 1) {
        s += __shfl_down(s, off, 64);
        c += __shfl_down(c, off, 64);
        w += __shfl_down(w, off, 64);
    }
    __shared__ double       fs[16];
    __shared__ unsigned int fc[16], fw[16];
    const int lane = tid & 63, wave = tid >> 6;
    if (lane == 0) { fs[wave] = s; fc[wave] = c; fw[wave] = w; }
    __syncthreads();
    if (tid == 0) {
        double ts = 0.0; unsigned int tc = 0u, tw = 0u;
        #pragma unroll
        for (int k = 0; k < 16; ++k) { ts += fs[k]; tc += fc[k]; tw += fw[k]; }
        const double loss_sb = (tc > 0u) ? (0.2 * ts / (double)tc) : 0.0;
        const double avg_factor = (double)tw + 1e-6;
        out[0] = (float)(loss_sb / avg_factor);
    }
}

extern "C" void kernel_launch(void* const* d_in, const int* in_sizes, int n_in,
                              void* d_out, int out_size, void* d_ws, size_t ws_size,
                              hipStream_t stream) {
    const float* pts    = (const float*)d_in[0];   // [n,18]
    const float* quads  = (const float*)d_in[1];   // [n,8]
    const float* weight = (const float*)d_in[2];   // [n]
    float* out = (float*)d_out;

    const int n = in_sizes[2];

    double*       part_sum  = (double*)d_ws;
    unsigned int* part_cnt  = (unsigned int*)((char*)d_ws + (size_t)SBL_GRID * sizeof(double));
    unsigned int* part_wpos = (unsigned int*)((char*)d_ws + (size_t)SBL_GRID * (sizeof(double) + sizeof(unsigned int)));

    sbl_main<<<SBL_GRID, SBL_BLOCK, 0, stream>>>(pts, quads, weight,
                                                 part_sum, part_cnt, part_wpos, n);
    sbl_finalize<<<1, 1024, 0, stream>>>(part_sum, part_cnt, part_wpos, out, SBL_GRID);
}

// Round 4
// 132.259 us; speedup vs baseline: 1.0496x; 1.0496x over previous
//
#include <hip/hip_runtime.h>
#include <cstdint>

// SpatialBorderLoss — R11: R9 structure (best, 133.28us) + raw v_sqrt_f32
// + vmcnt-only per-wave wait. Nothing else changed.
//
// R10 post-mortem (persistent grid + counted vmcnt(9)): REGRESSED, main
// 25 -> 44.9us, hbm 15% peak, occupancy 30%. All 4096 waves dump their
// prefetch groups at t=0 and then FIFO-wait on a ~70k-deep request queue;
// per-request latency scales with in-flight volume and the 1-deep pipeline
// can't cover it. R9's one-shot blocks + dispatcher block-turnover provide
// the same in-flight volume with smooth arrival — for pure streaming ops,
// block turnover BEATS an explicit persistent vmcnt pipeline (opposite of
// the GEMM regime). Also learned: FETCH_SIZE(main)=52.8MB — half the 108MB
// input is L3-resident from the harness fill; main's floor is ~14-17us.
//
// R11 delta: VALUBusy showed ~10us of real VALU work. Largest lump:
// non-fast-math sqrtf (library fixup, ~10 instr x 9M calls). Swap to raw
// v_sqrt_f32 (~1 ulp; sum is double-accumulated, tolerance ~2.5% rel).
// Predict: main -1..-2us, total ~131.5-133. If |delta|<1us -> roofline
// (remaining time = 2x43.5us harness fills + near-floor main).
//
// ws: double part_sum[nb] ; uint part_cnt[nb] ; uint part_wpos[nb]

#define SBL_BLOCK 512
#define SBL_TILE  512
#define SBL_WAVES (SBL_BLOCK / 64)
#define SBL_WAVE_BYTES (64 * 72)       // 4608 B = 64 rows of pts per wave

__device__ __forceinline__ float sbl_sqrtf(float x) {
#if __has_builtin(__builtin_amdgcn_sqrtf)
    return __builtin_amdgcn_sqrtf(x);   // raw v_sqrt_f32
#else
    return sqrtf(x);
#endif
}

__global__ void __launch_bounds__(SBL_BLOCK) sbl_main(
    const float* __restrict__ pts,      // [n,18]
    const float* __restrict__ quads,    // [n,8]
    const float* __restrict__ weight,   // [n]
    double* __restrict__ part_sum,
    unsigned int* __restrict__ part_cnt,
    unsigned int* __restrict__ part_wpos,
    int n)
{
    __shared__ __align__(16) float s_pts[SBL_TILE * 18];   // 36864 B

    const int tid  = threadIdx.x;
    const int lane = tid & 63;
    const int wave = tid >> 6;
    const int base = blockIdx.x * SBL_TILE;
    int rows = n - base; if (rows > SBL_TILE) rows = SBL_TILE;
    const bool have_row = (tid < rows);
    const bool full = (rows == SBL_TILE);

    // ---- stage pts: wave w DMAs its OWN 64 rows (wave-owned LDS region) ----
    // 4608 B per wave = 4 x (64 lanes x 16B) + 2 x (64 lanes x 4B).
    if (full) {
        const char* g0 = (const char*)pts + (size_t)base * 72
                       + (size_t)wave * SBL_WAVE_BYTES;
        const uint32_t l0 = (uint32_t)(uintptr_t)(void*)s_pts
                          + (uint32_t)(wave * SBL_WAVE_BYTES);
        #pragma unroll
        for (int i = 0; i < 4; ++i) {                    // 16B/lane, verified width
            __builtin_amdgcn_global_load_lds(
                (const __attribute__((address_space(1))) void*)(g0 + i * 1024 + lane * 16),
                (__attribute__((address_space(3))) void*)(uintptr_t)(l0 + i * 1024 + lane * 16),
                16, 0, 0);
        }
        #pragma unroll
        for (int j = 0; j < 2; ++j) {                    // 4B/lane, verified width
            __builtin_amdgcn_global_load_lds(
                (const __attribute__((address_space(1))) void*)(g0 + 4096 + j * 256 + lane * 4),
                (__attribute__((address_space(3))) void*)(uintptr_t)(l0 + 4096 + j * 256 + lane * 4),
                4, 0, 0);
        }
    } else {                                            // tail tile (once per grid)
        const float2* g2 = reinterpret_cast<const float2*>(pts + (size_t)base * 18);
        float2* s2 = reinterpret_cast<float2*>(s_pts);
        const int nf2 = rows * 9;
        for (int idx = tid; idx < nf2; idx += SBL_BLOCK) s2[idx] = g2[idx];
    }

    // ---- per-thread quad + weight loads (latency overlaps the LDS DMA) ----
    float4 qa = make_float4(0.f, 0.f, 0.f, 0.f);
    float4 qb = make_float4(0.f, 0.f, 0.f, 0.f);
    float wv = 0.0f;
    if (have_row) {
        const float4* q4 = reinterpret_cast<const float4*>(quads) + (size_t)(base + tid) * 2;
        qa = q4[0];
        qb = q4[1];
        wv = weight[base + tid];
    }

    if (full) {
        // per-wave wait: only THIS wave's DMA + register loads. No block barrier.
        asm volatile("s_waitcnt vmcnt(0)" ::: "memory");
        __builtin_amdgcn_sched_barrier(0);
    } else {
        __syncthreads();                                // tail path: cross-wave LDS writes
    }

    float local_sum = 0.0f;
    // pack: cnt in [15:0] (<=576 per wave), wpos in [31:16] (<=64 per wave)
    unsigned int pack = (wv > 0.0f) ? (1u << 16) : 0u;

    // ---- compute: thread t = row t, 9 points from wave-owned LDS region ----
    if (have_row) {
        const float vx0 = qa.x, vy0 = qa.y, vx1 = qa.z, vy1 = qa.w;
        const float vx2 = qb.x, vy2 = qb.y, vx3 = qb.z, vy3 = qb.w;
        const float cx = (vx0 + vx2) * 0.5f;
        const float cy = (vy0 + vy2) * 0.5f;
        // edge e pairs (v_e, v_{e-1 mod 4}) per jnp.roll(v,1)
        const float d0 = vy3 - vy0, d1 = vy0 - vy1, d2 = vy1 - vy2, d3 = vy2 - vy3;
        const float e0 = vx3 - vx0, e1 = vx0 - vx1, e2 = vx1 - vx2, e3 = vx2 - vx3;
        const bool  n0 = d0 < 0.0f, n1 = d1 < 0.0f, n2 = d2 < 0.0f, n3 = d3 < 0.0f;

        const float2* prow = reinterpret_cast<const float2*>(s_pts + tid * 18);
        #pragma unroll
        for (int k = 0; k < 9; ++k) {
            const float2 p = prow[k];
            const float px = p.x, py = p.y;

            const bool c0 = vy0 > py, c1 = vy1 > py, c2 = vy2 > py, c3 = vy3 > py;
            const bool s0 = c0 != c3, s1 = c1 != c0, s2 = c2 != c1, s3 = c3 != c2;

            // straddle pins sign of d; divide -> sign-adjusted mul-compare
            const float t0 = py - vy0, t1 = py - vy1, t2 = py - vy2, t3 = py - vy3;
            const float m0 = e0 * t0, m1 = e1 * t1, m2 = e2 * t2, m3 = e3 * t3;
            const float l0 = (px - vx0) * d0, l1 = (px - vx1) * d1;
            const float l2 = (px - vx2) * d2, l3 = (px - vx3) * d3;

            const bool x0 = s0 && ((l0 < m0) != n0);
            const bool x1 = s1 && ((l1 < m1) != n1);
            const bool x2 = s2 && ((l2 < m2) != n2);
            const bool x3 = s3 && ((l3 < m3) != n3);

            const bool inside = (x0 != x1) != (x2 != x3);   // parity of crossings
            if (!inside) {
                const float dx = px - cx;
                const float dy = py - cy;
                local_sum += sbl_sqrtf(fmaf(dx, dx, dy * dy));  // 0.2 applied in finalize
                pack += 1u;
            }
        }
    }

    // ---- wave (64) reduction ----
    #pragma unroll
    for (int off = 32; off > 0; off >>= 1) {
        local_sum += __shfl_down(local_sum, off, 64);
        pack      += __shfl_down(pack, off, 64);
    }

    // ---- block reduction across waves ----
    __shared__ float        r_sum[SBL_WAVES];
    __shared__ unsigned int r_pack[SBL_WAVES];
    if (lane == 0) { r_sum[wave] = local_sum; r_pack[wave] = pack; }
    __syncthreads();
    if (tid == 0) {
        double bsum = 0.0;
        unsigned int bcnt = 0u, bwpos = 0u;
        #pragma unroll
        for (int i = 0; i < SBL_WAVES; ++i) {
            bsum  += (double)r_sum[i];
            bcnt  += r_pack[i] & 0xffffu;
            bwpos += r_pack[i] >> 16;
        }
        part_sum[blockIdx.x]  = bsum;      // own slot: no init, no atomics
        part_cnt[blockIdx.x]  = bcnt;
        part_wpos[blockIdx.x] = bwpos;
    }
}

__global__ void __launch_bounds__(1024) sbl_finalize(
    const double* __restrict__ part_sum,
    const unsigned int* __restrict__ part_cnt,
    const unsigned int* __restrict__ part_wpos,
    float* __restrict__ out,
    int nblocks)
{
    const int tid = threadIdx.x;           // 1024 threads = 16 waves
    double s = 0.0;
    unsigned int c = 0u, w = 0u;
    for (int i = tid; i < nblocks; i += 1024) {   // 2 independent iterations
        s += part_sum[i];
        c += part_cnt[i];
        w += part_wpos[i];
    }
    #pragma unroll
    for (int off = 32; off > 0; off >>= 1) {
        s += __shfl_down(s, off, 64);
        c += __shfl_down(c, off, 64);
        w += __shfl_down(w, off, 64);
    }
    __shared__ double       fs[16];
    __shared__ unsigned int fc[16], fw[16];
    const int lane = tid & 63, wave = tid >> 6;
    if (lane == 0) { fs[wave] = s; fc[wave] = c; fw[wave] = w; }
    __syncthreads();
    if (tid == 0) {
        double ts = 0.0; unsigned int tc = 0u, tw = 0u;
        #pragma unroll
        for (int k = 0; k < 16; ++k) { ts += fs[k]; tc += fc[k]; tw += fw[k]; }
        const double loss_sb = (tc > 0u) ? (0.2 * ts / (double)tc) : 0.0;
        const double avg_factor = (double)tw + 1e-6;
        out[0] = (float)(loss_sb / avg_factor);
    }
}

extern "C" void kernel_launch(void* const* d_in, const int* in_sizes, int n_in,
                              void* d_out, int out_size, void* d_ws, size_t ws_size,
                              hipStream_t stream) {
    const float* pts    = (const float*)d_in[0];   // [n,18]
    const float* quads  = (const float*)d_in[1];   // [n,8]
    const float* weight = (const float*)d_in[2];   // [n]
    float* out = (float*)d_out;

    const int n = in_sizes[2];
    const int nblocks = (n + SBL_TILE - 1) / SBL_TILE;

    double*       part_sum  = (double*)d_ws;
    unsigned int* part_cnt  = (unsigned int*)((char*)d_ws + (size_t)nblocks * sizeof(double));
    unsigned int* part_wpos = (unsigned int*)((char*)d_ws + (size_t)nblocks * (sizeof(double) + sizeof(unsigned int)));

    sbl_main<<<nblocks, SBL_BLOCK, 0, stream>>>(pts, quads, weight,
                                                part_sum, part_cnt, part_wpos, n);
    sbl_finalize<<<1, 1024, 0, stream>>>(part_sum, part_cnt, part_wpos, out, nblocks);
}